// Round 2
// baseline (1710.239 us; speedup 1.0000x reference)
//
#include <hip/hip_runtime.h>
#include <hip/hip_bf16.h>
#include <math.h>

#define BB 8
#define TT 4096
#define CC 512
#define BT (BB*TT)
#define KD 256
#define VD 512
#define NSEG 32
#define SEG 128

using bf16 = __hip_bfloat16;
typedef __attribute__((ext_vector_type(4))) float f32x4;
typedef __attribute__((ext_vector_type(8))) short s16x8;

static __device__ __forceinline__ float bf2f(bf16 x){ return __bfloat162float(x); }
static __device__ __forceinline__ bf16 f2bf(float x){ return __float2bfloat16(x); }

// ---------------- weight convert+transpose: dst[Npad][K] = src[k][n] (bf16, zero pad) ---------
__global__ void wconv_t(const float* __restrict__ src, bf16* __restrict__ dst, int K, int N, int Npad){
  int idx = blockIdx.x*256 + threadIdx.x;
  if (idx >= K*Npad) return;
  int n = idx / K, k = idx % K;
  float v = (n < N) ? src[(size_t)k*N + n] : 0.f;
  dst[idx] = f2bf(v);
}

// ---------------- LayerNorm over C=512, block per row, bf16 out ----------------
__global__ __launch_bounds__(256) void ln_bf16(const float* __restrict__ x, const float* __restrict__ w,
                                               const float* __restrict__ b, bf16* __restrict__ out){
  int bt = blockIdx.x;
  const float* row = x + (size_t)bt*CC;
  int t = threadIdx.x;
  float a0 = row[t], a1 = row[t+256];
  float s = a0 + a1, ss = a0*a0 + a1*a1;
  for (int off=32; off; off>>=1){ s += __shfl_down(s, off, 64); ss += __shfl_down(ss, off, 64); }
  __shared__ float ps[4], pss[4];
  int wv = t>>6, ln = t&63;
  if (ln==0){ ps[wv]=s; pss[wv]=ss; }
  __syncthreads();
  if (t==0){
    float S=ps[0]+ps[1]+ps[2]+ps[3], SS=pss[0]+pss[1]+pss[2]+pss[3];
    float mu = S/CC; float var = SS/CC - mu*mu;
    ps[0]=mu; pss[0]=rsqrtf(var+1e-5f);
  }
  __syncthreads();
  float mu = ps[0], inv = pss[0];
  out[(size_t)bt*CC + t]     = f2bf((a0-mu)*inv*w[t]+b[t]);
  out[(size_t)bt*CC + t+256] = f2bf((a1-mu)*inv*w[t+256]+b[t+256]);
}

// ---------------- xm = h + (shift(h)-h)*mu_x  (bf16 in/out) ----------------
__global__ void build_xm(const bf16* __restrict__ h, const float* __restrict__ mu_x, bf16* __restrict__ xm){
  size_t idx = (size_t)blockIdx.x*256 + threadIdx.x;
  int c = (int)(idx & (CC-1));
  size_t bt = idx >> 9;
  float hv = bf2f(h[idx]);
  float hp = (bt & (TT-1)) ? bf2f(h[idx - CC]) : 0.f;
  xm[idx] = f2bf(hv + (hp - hv)*mu_x[c]);
}

// ---------------- single lerp-mix build: hm = h + (hprev-h)*(xx_i @ W_x2[i] + bias_i) -------
__global__ __launch_bounds__(128) void build_hm(const bf16* __restrict__ h, const bf16* __restrict__ xx,
        const float* __restrict__ W_x2i, const float* __restrict__ x_biasi, bf16* __restrict__ hm){
  int bt0 = blockIdx.x*16;
  int c = blockIdx.y*128 + threadIdx.x;
  float W[32];
  #pragma unroll
  for (int r=0;r<32;r++) W[r] = W_x2i[(size_t)r*CC + c];
  float bia = x_biasi[c];
  #pragma unroll 1
  for (int j=0;j<16;j++){
    int bt = bt0+j;
    float hv = bf2f(h[(size_t)bt*CC + c]);
    float hp = ((bt & (TT-1)) != 0) ? bf2f(h[(size_t)(bt-1)*CC + c]) : 0.f;
    const bf16* xr = xx + (size_t)bt*192;
    float acc = bia;
    #pragma unroll
    for (int r=0;r<32;r++) acc += bf2f(xr[r])*W[r];
    hm[(size_t)bt*CC + c] = f2bf(hv + (hp-hv)*acc);
  }
}

// ---------------- bf16 MFMA GEMM: Out[M,N] = A[M,K] @ Bt[N,K]^T, fused epilogues -------------
enum {EP_BF16, EP_TANH_BF16, EP_NEGEXP_F32, EP_RES_F32, EP_RELU2_BF16, EP_SIG_BF16, EP_FINAL_F32};

template<int MODE>
__global__ __launch_bounds__(256) void gemm_bf16(
    const bf16* __restrict__ A, const bf16* __restrict__ Bt, void* __restrict__ Out,
    int N, int K, const float* __restrict__ auxf, const bf16* __restrict__ auxb,
    const float* __restrict__ bias)
{
  __shared__ bf16 Al[128][40];
  __shared__ bf16 Bl[64][40];
  int tid = threadIdx.x;
  int m0 = blockIdx.x*128, n0 = blockIdx.y*64;
  int wv = tid>>6, ln = tid&63;
  f32x4 acc[2][4];
  #pragma unroll
  for(int f=0;f<2;f++) for(int c=0;c<4;c++){ f32x4 z = {0.f,0.f,0.f,0.f}; acc[f][c]=z; }
  const int nkt = K>>5;
  for (int kt=0; kt<nkt; kt++){
    __syncthreads();
    {
      int c0 = tid, c1 = tid+256;
      int r = c0>>2, ko=(c0&3)*8;
      *(uint4*)&Al[r][ko] = *(const uint4*)&A[(size_t)(m0+r)*K + kt*32 + ko];
      r = c1>>2; ko=(c1&3)*8;
      *(uint4*)&Al[r][ko] = *(const uint4*)&A[(size_t)(m0+r)*K + kt*32 + ko];
      r = tid>>2; ko=(tid&3)*8;
      *(uint4*)&Bl[r][ko] = *(const uint4*)&Bt[(size_t)(n0+r)*K + kt*32 + ko];
    }
    __syncthreads();
    int ks = (ln>>4)*8;
    s16x8 af0 = *(const s16x8*)&Al[wv*32 + (ln&15)][ks];
    s16x8 af1 = *(const s16x8*)&Al[wv*32 + 16 + (ln&15)][ks];
    #pragma unroll
    for (int c=0;c<4;c++){
      s16x8 bfr = *(const s16x8*)&Bl[c*16 + (ln&15)][ks];
      acc[0][c] = __builtin_amdgcn_mfma_f32_16x16x32_bf16(af0, bfr, acc[0][c], 0,0,0);
      acc[1][c] = __builtin_amdgcn_mfma_f32_16x16x32_bf16(af1, bfr, acc[1][c], 0,0,0);
    }
  }
  #pragma unroll
  for (int f=0; f<2; f++) for (int c=0;c<4;c++){
    int col = n0 + c*16 + (ln&15);
    int rbase = m0 + wv*32 + f*16 + (ln>>4)*4;
    #pragma unroll
    for (int j=0;j<4;j++){
      size_t idx = (size_t)(rbase+j)*N + col;
      float val = acc[f][c][j];
      if constexpr(MODE==EP_BF16)           ((bf16*)Out)[idx] = f2bf(val);
      else if constexpr(MODE==EP_TANH_BF16) ((bf16*)Out)[idx] = f2bf(tanhf(val));
      else if constexpr(MODE==EP_NEGEXP_F32){ float w = -expf(val + bias[col]); ((float*)Out)[idx] = fmaxf(w, -20.f); }
      else if constexpr(MODE==EP_RES_F32)   ((float*)Out)[idx] = auxf[idx] + val;
      else if constexpr(MODE==EP_RELU2_BF16){ float m = fmaxf(val,0.f); ((bf16*)Out)[idx] = f2bf(m*m); }
      else if constexpr(MODE==EP_SIG_BF16)  ((bf16*)Out)[idx] = f2bf(1.f/(1.f+expf(-val)));
      else if constexpr(MODE==EP_FINAL_F32) ((float*)Out)[idx] = auxf[idx] + bf2f(auxb[idx])*val;
    }
  }
}

// ---------------- WKV6 segment scan ----------------
// P0: per-(b,h,seg) total decay  D[k] = exp(sum_t wd)
__global__ __launch_bounds__(64) void wkv_p0(const float* __restrict__ wd, float* __restrict__ Dseg){
  int bhs = blockIdx.x;
  int bh = bhs / NSEG, seg = bhs % NSEG;
  int b = bh >> 2, h = bh & 3;
  int k = threadIdx.x;
  size_t base = ((size_t)b*TT + (size_t)seg*SEG)*KD + h*64 + k;
  float s = 0.f;
  for (int t=0;t<SEG;t++) s += wd[base + (size_t)t*KD];
  Dseg[(size_t)bhs*64 + k] = expf(s);
}

// P1: per-(b,h,seg) local decay-weighted KV sum M[k][v]
__global__ __launch_bounds__(64) void wkv_p1(const bf16* __restrict__ kbuf, const bf16* __restrict__ vbuf,
      const float* __restrict__ wd, float* __restrict__ Mseg){
  int bhs = blockIdx.x; int bh = bhs/NSEG, seg = bhs%NSEG;
  int b = bh>>2, h = bh&3;
  int ln = threadIdx.x;
  __shared__ float ew[32][64], qk[32][64], vv[32][128];
  float Sa[64], Sb[64];
  #pragma unroll
  for (int k=0;k<64;k++){ Sa[k]=0.f; Sb[k]=0.f; }
  int t0g = seg*SEG;
  #pragma unroll 1
  for (int sub=0; sub<SEG/32; sub++){
    __syncthreads();
    for (int idx=ln; idx<32*64; idx+=64){
      int t = idx>>6, k = idx&63;
      size_t gi = ((size_t)b*TT + t0g + sub*32 + t)*KD + h*64 + k;
      ew[t][k] = expf(wd[gi]);
      qk[t][k] = bf2f(kbuf[gi]);
    }
    for (int idx=ln; idx<32*128; idx+=64){
      int t = idx>>7, vx = idx&127;
      vv[t][vx] = bf2f(vbuf[((size_t)b*TT + t0g + sub*32 + t)*VD + h*128 + vx]);
    }
    __syncthreads();
    #pragma unroll 1
    for (int t=0;t<32;t++){
      float va = vv[t][ln], vb = vv[t][ln+64];
      #pragma unroll
      for (int k=0;k<64;k++){
        float e = ew[t][k], q = qk[t][k];
        Sa[k] = e*Sa[k] + q*va;
        Sb[k] = e*Sb[k] + q*vb;
      }
    }
  }
  float* M = Mseg + (size_t)bhs*64*128;
  #pragma unroll
  for (int k=0;k<64;k++){ M[k*128 + ln] = Sa[k]; M[k*128 + ln + 64] = Sb[k]; }
}

// P2: sequential combine across segments, IN-PLACE (Mseg becomes Sstart)
__global__ __launch_bounds__(512) void wkv_p2(float* __restrict__ MS, const float* __restrict__ Dseg){
  int bh = blockIdx.x >> 2;
  int vq = blockIdx.x & 3;
  int tid = threadIdx.x;
  float S[4] = {0.f,0.f,0.f,0.f};
  #pragma unroll 1
  for (int seg=0; seg<NSEG; seg++){
    size_t base = ((size_t)bh*NSEG + seg)*64*128;
    const float* D = Dseg + ((size_t)bh*NSEG + seg)*64;
    #pragma unroll
    for (int j=0;j<4;j++){
      int e = tid + j*512;
      int k = e>>5, v = vq*32 + (e&31);
      float m = MS[base + k*128 + v];
      MS[base + k*128 + v] = S[j];
      S[j] = D[k]*S[j] + m;
    }
  }
}

// P3: per-(b,h,seg) outputs with fused GroupNorm + silu(g) gate -> bf16 gated
__global__ __launch_bounds__(64) void wkv_p3(const bf16* __restrict__ rbuf, const bf16* __restrict__ kbuf,
     const bf16* __restrict__ vbuf, const float* __restrict__ wd, const float* __restrict__ Sstart,
     const float* __restrict__ uu, const bf16* __restrict__ gg,
     const float* __restrict__ gn_w, const float* __restrict__ gn_b, bf16* __restrict__ gated){
  int bhs = blockIdx.x; int bh = bhs/NSEG, seg = bhs%NSEG;
  int b = bh>>2, h = bh&3;
  int ln = threadIdx.x;
  __shared__ float ew[32][64], qk[32][64], rr[32][64], vv[32][128];
  __shared__ float ul[64];
  ul[ln] = uu[h*64 + ln];
  float gnw0 = gn_w[h*128+ln], gnw1 = gn_w[h*128+64+ln];
  float gnb0 = gn_b[h*128+ln], gnb1 = gn_b[h*128+64+ln];
  float Sa[64], Sb[64];
  const float* Sst = Sstart + (size_t)bhs*64*128;
  #pragma unroll
  for (int k=0;k<64;k++){ Sa[k] = Sst[k*128+ln]; Sb[k] = Sst[k*128+ln+64]; }
  int t0g = seg*SEG;
  #pragma unroll 1
  for (int sub=0; sub<SEG/32; sub++){
    __syncthreads();
    for (int idx=ln; idx<32*64; idx+=64){
      int t=idx>>6, k=idx&63;
      size_t gi = ((size_t)b*TT + t0g + sub*32 + t)*KD + h*64 + k;
      ew[t][k]=expf(wd[gi]); qk[t][k]=bf2f(kbuf[gi]); rr[t][k]=bf2f(rbuf[gi]);
    }
    for (int idx=ln; idx<32*128; idx+=64){
      int t=idx>>7, vx=idx&127;
      vv[t][vx] = bf2f(vbuf[((size_t)b*TT + t0g+sub*32+t)*VD + h*128 + vx]);
    }
    __syncthreads();
    #pragma unroll 1
    for (int t=0;t<32;t++){
      float va = vv[t][ln], vb = vv[t][ln+64];
      float oa=0.f, ob=0.f, bb=0.f;
      #pragma unroll
      for (int k=0;k<64;k++){
        float e=ew[t][k], q=qk[t][k], r=rr[t][k];
        oa += r*Sa[k]; ob += r*Sb[k];
        bb += r*q*ul[k];
        Sa[k] = e*Sa[k] + q*va;
        Sb[k] = e*Sb[k] + q*vb;
      }
      oa += bb*va; ob += bb*vb;
      // fused GroupNorm over this head's 128 channels (held across the wave)
      float s = oa+ob, ss = oa*oa+ob*ob;
      #pragma unroll
      for (int off=32; off; off>>=1){ s += __shfl_xor(s,off,64); ss += __shfl_xor(ss,off,64); }
      float mu = s*(1.f/128.f);
      float inv = rsqrtf(fmaxf(ss*(1.f/128.f) - mu*mu, 0.f) + 1e-5f);
      float xa = (oa-mu)*inv*gnw0 + gnb0;
      float xb = (ob-mu)*inv*gnw1 + gnb1;
      size_t go = ((size_t)b*TT + t0g + sub*32 + t)*VD + h*128;
      float ga = bf2f(gg[go+ln]), gb = bf2f(gg[go+ln+64]);
      xa *= ga/(1.f+expf(-ga));
      xb *= gb/(1.f+expf(-gb));
      gated[go+ln] = f2bf(xa);
      gated[go+ln+64] = f2bf(xb);
    }
  }
}

// ---------------- FFN lerp inputs (bf16 in/out) ----------------
__global__ void build_ffn_in(const bf16* __restrict__ hn, const float* __restrict__ mu_k,
                             const float* __restrict__ mu_r, bf16* __restrict__ kin, bf16* __restrict__ rin){
  size_t idx = (size_t)blockIdx.x*256 + threadIdx.x;
  int c = (int)(idx & (CC-1));
  size_t bt = idx >> 9;
  float hv = bf2f(hn[idx]);
  float hp = (bt & (TT-1)) ? bf2f(hn[idx - CC]) : 0.f;
  float d = hp - hv;
  kin[idx] = f2bf(hv + d*mu_k[c]);
  rin[idx] = f2bf(hv + d*mu_r[c]);
}

// ---------------- compact workspace arena (bytes), peak ~246 MiB ----------------
#define MiB 1048576ull
static constexpr size_t OFF_H1   = 0;           // bf16 BT*C (32)   ; later RF bf16 (32)
static constexpr size_t OFF_XX   = 32*MiB;      // bf16 BT*192 (12)
static constexpr size_t OFF_HM   = 44*MiB;      // bf16 BT*C (32)   ; xm -> hm_i -> GATED -> KIN
static constexpr size_t OFF_R    = 76*MiB;      // bf16 BT*256 (16) ; later HN (with K slot, 32)
static constexpr size_t OFF_K    = 92*MiB;      // bf16 BT*256 (16)
static constexpr size_t OFF_V    = 108*MiB;     // bf16 BT*512 (32) ; later RIN
static constexpr size_t OFF_WD   = 140*MiB;     // f32 BT*256 (32)  ; later KF part 1
static constexpr size_t OFF_G    = 172*MiB;     // bf16 BT*512 (32) ; later KF part 2 (KF=64 @140)
static constexpr size_t OFF_MSEG = 204*MiB;     // f32 1024*64*128 (32), in-place -> Sstart
static constexpr size_t OFF_W1T  = 236*MiB;     // bf16 BT*64 (4)
static constexpr size_t OFF_DSEG = 240*MiB;     // f32 1024*64 (0.25)
static constexpr size_t WT_X1  = 241*MiB;
static constexpr size_t WT_R   = WT_X1  + 196608;
static constexpr size_t WT_K   = WT_R   + 262144;
static constexpr size_t WT_V   = WT_K   + 262144;
static constexpr size_t WT_G   = WT_V   + 524288;
static constexpr size_t WT_W1  = WT_G   + 524288;
static constexpr size_t WT_W2  = WT_W1  + 65536;
static constexpr size_t WT_O   = WT_W2  + 32768;
static constexpr size_t WT_KEY = WT_O   + 524288;
static constexpr size_t WT_REC = WT_KEY + 1048576;
static constexpr size_t WT_VAL = WT_REC + 524288;
static constexpr size_t WS_NEED = WT_VAL + 1048576;

extern "C" void kernel_launch(void* const* d_in, const int* in_sizes, int n_in,
                              void* d_out, int out_size, void* d_ws, size_t ws_size,
                              hipStream_t stream){
  (void)in_sizes; (void)n_in; (void)out_size;
  if (ws_size < WS_NEED) return;   // clean failure instead of OOB fault
  const float* x      = (const float*)d_in[0];
  const float* ln1w   = (const float*)d_in[1];
  const float* ln1b   = (const float*)d_in[2];
  const float* mu_x   = (const float*)d_in[3];
  const float* W_x1   = (const float*)d_in[4];
  const float* W_x2   = (const float*)d_in[5];
  const float* x_bias = (const float*)d_in[6];
  const float* W_r    = (const float*)d_in[7];
  const float* W_k    = (const float*)d_in[8];
  const float* W_v    = (const float*)d_in[9];
  const float* W_g    = (const float*)d_in[10];
  const float* W_w1   = (const float*)d_in[11];
  const float* W_w2   = (const float*)d_in[12];
  const float* b_w2   = (const float*)d_in[13];
  const float* u      = (const float*)d_in[14];
  const float* gn_w   = (const float*)d_in[15];
  const float* gn_b   = (const float*)d_in[16];
  const float* W_o    = (const float*)d_in[17];
  const float* ln2w   = (const float*)d_in[18];
  const float* ln2b   = (const float*)d_in[19];
  const float* mu_k   = (const float*)d_in[20];
  const float* W_key  = (const float*)d_in[21];
  const float* mu_r   = (const float*)d_in[22];
  const float* W_rec  = (const float*)d_in[23];
  const float* W_val  = (const float*)d_in[24];
  char* ws = (char*)d_ws;
  auto F  = [&](size_t off){ return (float*)(ws+off); };
  auto Bf = [&](size_t off){ return (bf16*)(ws+off); };
  float* h2 = (float*)d_out;   // attn-out residual lives in d_out

  auto wc = [&](const float* src, size_t dstoff, int K, int N, int Npad){
    int tot = K*Npad;
    wconv_t<<<(tot+255)/256, 256, 0, stream>>>(src, Bf(dstoff), K, N, Npad);
  };
  wc(W_x1, WT_X1, 512, 160, 192);
  wc(W_r,  WT_R,  512, 256, 256);
  wc(W_k,  WT_K,  512, 256, 256);
  wc(W_v,  WT_V,  512, 512, 512);
  wc(W_g,  WT_G,  512, 512, 512);
  wc(W_w1, WT_W1, 512, 64, 64);
  wc(W_w2, WT_W2, 64, 256, 256);
  wc(W_o,  WT_O,  512, 512, 512);
  wc(W_key,WT_KEY,512, 1024, 1024);
  wc(W_rec,WT_REC,512, 512, 512);
  wc(W_val,WT_VAL,1024, 512, 512);

  // ---- attention pre-projections ----
  ln_bf16<<<BT,256,0,stream>>>(x, ln1w, ln1b, Bf(OFF_H1));
  build_xm<<<BT*CC/256,256,0,stream>>>(Bf(OFF_H1), mu_x, Bf(OFF_HM));
  gemm_bf16<EP_TANH_BF16><<<dim3(BT/128,3),256,0,stream>>>(Bf(OFF_HM), Bf(WT_X1), Bf(OFF_XX), 192,512, nullptr,nullptr,nullptr);

  for (int i=0;i<5;i++){
    build_hm<<<dim3(BT/16,4),128,0,stream>>>(Bf(OFF_H1), Bf(OFF_XX)+i*32, W_x2 + (size_t)i*32*CC, x_bias + i*CC, Bf(OFF_HM));
    if (i==0)      gemm_bf16<EP_BF16><<<dim3(BT/128,4),256,0,stream>>>(Bf(OFF_HM), Bf(WT_R), Bf(OFF_R), 256,512, nullptr,nullptr,nullptr);
    else if (i==1){
      gemm_bf16<EP_TANH_BF16><<<dim3(BT/128,1),256,0,stream>>>(Bf(OFF_HM), Bf(WT_W1), Bf(OFF_W1T), 64,512, nullptr,nullptr,nullptr);
      gemm_bf16<EP_NEGEXP_F32><<<dim3(BT/128,4),256,0,stream>>>(Bf(OFF_W1T), Bf(WT_W2), F(OFF_WD), 256,64, nullptr,nullptr,b_w2);
    }
    else if (i==2) gemm_bf16<EP_BF16><<<dim3(BT/128,4),256,0,stream>>>(Bf(OFF_HM), Bf(WT_K), Bf(OFF_K), 256,512, nullptr,nullptr,nullptr);
    else if (i==3) gemm_bf16<EP_BF16><<<dim3(BT/128,8),256,0,stream>>>(Bf(OFF_HM), Bf(WT_V), Bf(OFF_V), 512,512, nullptr,nullptr,nullptr);
    else           gemm_bf16<EP_BF16><<<dim3(BT/128,8),256,0,stream>>>(Bf(OFF_HM), Bf(WT_G), Bf(OFF_G), 512,512, nullptr,nullptr,nullptr);
  }

  // ---- WKV6 segment scan ----
  wkv_p0<<<BB*4*NSEG,64,0,stream>>>(F(OFF_WD), F(OFF_DSEG));
  wkv_p1<<<BB*4*NSEG,64,0,stream>>>(Bf(OFF_K), Bf(OFF_V), F(OFF_WD), F(OFF_MSEG));
  wkv_p2<<<BB*4*4,512,0,stream>>>(F(OFF_MSEG), F(OFF_DSEG));
  wkv_p3<<<BB*4*NSEG,64,0,stream>>>(Bf(OFF_R), Bf(OFF_K), Bf(OFF_V), F(OFF_WD), F(OFF_MSEG), u,
                                    Bf(OFF_G), gn_w, gn_b, Bf(OFF_HM));

  // ---- output projection + residual -> h2 (in d_out) ----
  gemm_bf16<EP_RES_F32><<<dim3(BT/128,8),256,0,stream>>>(Bf(OFF_HM), Bf(WT_O), h2, 512,512, x,nullptr,nullptr);

  // ---- channel mixing (FFN) ----
  ln_bf16<<<BT,256,0,stream>>>(h2, ln2w, ln2b, Bf(OFF_R));
  build_ffn_in<<<BT*CC/256,256,0,stream>>>(Bf(OFF_R), mu_k, mu_r, Bf(OFF_HM), Bf(OFF_V));
  gemm_bf16<EP_RELU2_BF16><<<dim3(BT/128,16),256,0,stream>>>(Bf(OFF_HM), Bf(WT_KEY), Bf(OFF_WD), 1024,512, nullptr,nullptr,nullptr);
  gemm_bf16<EP_SIG_BF16><<<dim3(BT/128,8),256,0,stream>>>(Bf(OFF_V), Bf(WT_REC), Bf(OFF_H1), 512,512, nullptr,nullptr,nullptr);
  gemm_bf16<EP_FINAL_F32><<<dim3(BT/128,8),256,0,stream>>>(Bf(OFF_WD), Bf(WT_VAL), h2, 512,1024, h2, Bf(OFF_H1), nullptr);
}

// Round 3
// 1099.996 us; speedup vs baseline: 1.5548x; 1.5548x over previous
//
#include <hip/hip_runtime.h>
#include <hip/hip_bf16.h>
#include <math.h>

#define BB 8
#define TT 4096
#define CC 512
#define BT (BB*TT)
#define KD 256
#define VD 512
#define NSUB 64
#define SUB 64

using bf16 = __hip_bfloat16;
typedef __attribute__((ext_vector_type(4))) float f32x4;
typedef __attribute__((ext_vector_type(8))) short s16x8;
typedef __attribute__((ext_vector_type(8))) unsigned short u16x8;

static __device__ __forceinline__ float bf2f(bf16 x){ return __bfloat162float(x); }
static __device__ __forceinline__ bf16 f2bf(float x){ return __float2bfloat16(x); }
static __device__ __forceinline__ float bfbits(unsigned short u){
  union { unsigned int i; float f; } x; x.i = ((unsigned int)u)<<16; return x.f;
}
static __device__ __forceinline__ unsigned short f2bfbits(float f){
  union { bf16 b; unsigned short u; } x; x.b = f2bf(f); return x.u;
}

// ---------------- weight convert+transpose: dst[Npad][K] = src[k][n] (bf16, zero pad) ---------
__global__ void wconv_t(const float* __restrict__ src, bf16* __restrict__ dst, int K, int N, int Npad){
  int idx = blockIdx.x*256 + threadIdx.x;
  if (idx >= K*Npad) return;
  int n = idx / K, k = idx % K;
  float v = (n < N) ? src[(size_t)k*N + n] : 0.f;
  dst[idx] = f2bf(v);
}

// ---------------- LayerNorm over C=512, block per row, bf16 out ----------------
__global__ __launch_bounds__(256) void ln_bf16(const float* __restrict__ x, const float* __restrict__ w,
                                               const float* __restrict__ b, bf16* __restrict__ out){
  int bt = blockIdx.x;
  const float* row = x + (size_t)bt*CC;
  int t = threadIdx.x;
  float a0 = row[t], a1 = row[t+256];
  float s = a0 + a1, ss = a0*a0 + a1*a1;
  for (int off=32; off; off>>=1){ s += __shfl_down(s, off, 64); ss += __shfl_down(ss, off, 64); }
  __shared__ float ps[4], pss[4];
  int wv = t>>6, ln = t&63;
  if (ln==0){ ps[wv]=s; pss[wv]=ss; }
  __syncthreads();
  if (t==0){
    float S=ps[0]+ps[1]+ps[2]+ps[3], SS=pss[0]+pss[1]+pss[2]+pss[3];
    float mu = S/CC; float var = SS/CC - mu*mu;
    ps[0]=mu; pss[0]=rsqrtf(var+1e-5f);
  }
  __syncthreads();
  float mu = ps[0], inv = pss[0];
  out[(size_t)bt*CC + t]     = f2bf((a0-mu)*inv*w[t]+b[t]);
  out[(size_t)bt*CC + t+256] = f2bf((a1-mu)*inv*w[t+256]+b[t+256]);
}

// ---------------- xm = h + (shift(h)-h)*mu_x  (bf16 in/out) ----------------
__global__ void build_xm(const bf16* __restrict__ h, const float* __restrict__ mu_x, bf16* __restrict__ xm){
  size_t idx = (size_t)blockIdx.x*256 + threadIdx.x;
  int c = (int)(idx & (CC-1));
  size_t bt = idx >> 9;
  float hv = bf2f(h[idx]);
  float hp = (bt & (TT-1)) ? bf2f(h[idx - CC]) : 0.f;
  xm[idx] = f2bf(hv + (hp - hv)*mu_x[c]);
}

// ---------------- single lerp-mix build: hm = h + (hprev-h)*(xx_i @ W_x2[i] + bias_i) -------
__global__ __launch_bounds__(128) void build_hm(const bf16* __restrict__ h, const bf16* __restrict__ xx,
        const float* __restrict__ W_x2i, const float* __restrict__ x_biasi, bf16* __restrict__ hm){
  int bt0 = blockIdx.x*16;
  int c = blockIdx.y*128 + threadIdx.x;
  float W[32];
  #pragma unroll
  for (int r=0;r<32;r++) W[r] = W_x2i[(size_t)r*CC + c];
  float bia = x_biasi[c];
  #pragma unroll 1
  for (int j=0;j<16;j++){
    int bt = bt0+j;
    float hv = bf2f(h[(size_t)bt*CC + c]);
    float hp = ((bt & (TT-1)) != 0) ? bf2f(h[(size_t)(bt-1)*CC + c]) : 0.f;
    const bf16* xr = xx + (size_t)bt*192;
    float acc = bia;
    #pragma unroll
    for (int r=0;r<32;r++) acc += bf2f(xr[r])*W[r];
    hm[(size_t)bt*CC + c] = f2bf(hv + (hp-hv)*acc);
  }
}

// ---------------- bf16 MFMA GEMM: Out[M,N] = A[M,K] @ Bt[N,K]^T, fused epilogues -------------
enum {EP_BF16, EP_TANH_BF16, EP_NEGEXP_F32, EP_RES_F32, EP_RELU2_BF16, EP_SIG_BF16, EP_FINAL_F32};

template<int MODE>
__global__ __launch_bounds__(256) void gemm_bf16(
    const bf16* __restrict__ A, const bf16* __restrict__ Bt, void* __restrict__ Out,
    int N, int K, const float* __restrict__ auxf, const bf16* __restrict__ auxb,
    const float* __restrict__ bias)
{
  __shared__ bf16 Al[128][40];
  __shared__ bf16 Bl[64][40];
  int tid = threadIdx.x;
  int m0 = blockIdx.x*128, n0 = blockIdx.y*64;
  int wv = tid>>6, ln = tid&63;
  f32x4 acc[2][4];
  #pragma unroll
  for(int f=0;f<2;f++) for(int c=0;c<4;c++){ f32x4 z = {0.f,0.f,0.f,0.f}; acc[f][c]=z; }
  const int nkt = K>>5;
  for (int kt=0; kt<nkt; kt++){
    __syncthreads();
    {
      int c0 = tid, c1 = tid+256;
      int r = c0>>2, ko=(c0&3)*8;
      *(uint4*)&Al[r][ko] = *(const uint4*)&A[(size_t)(m0+r)*K + kt*32 + ko];
      r = c1>>2; ko=(c1&3)*8;
      *(uint4*)&Al[r][ko] = *(const uint4*)&A[(size_t)(m0+r)*K + kt*32 + ko];
      r = tid>>2; ko=(tid&3)*8;
      *(uint4*)&Bl[r][ko] = *(const uint4*)&Bt[(size_t)(n0+r)*K + kt*32 + ko];
    }
    __syncthreads();
    int ks = (ln>>4)*8;
    s16x8 af0 = *(const s16x8*)&Al[wv*32 + (ln&15)][ks];
    s16x8 af1 = *(const s16x8*)&Al[wv*32 + 16 + (ln&15)][ks];
    #pragma unroll
    for (int c=0;c<4;c++){
      s16x8 bfr = *(const s16x8*)&Bl[c*16 + (ln&15)][ks];
      acc[0][c] = __builtin_amdgcn_mfma_f32_16x16x32_bf16(af0, bfr, acc[0][c], 0,0,0);
      acc[1][c] = __builtin_amdgcn_mfma_f32_16x16x32_bf16(af1, bfr, acc[1][c], 0,0,0);
    }
  }
  #pragma unroll
  for (int f=0; f<2; f++) for (int c=0;c<4;c++){
    int col = n0 + c*16 + (ln&15);
    int rbase = m0 + wv*32 + f*16 + (ln>>4)*4;
    #pragma unroll
    for (int j=0;j<4;j++){
      size_t idx = (size_t)(rbase+j)*N + col;
      float val = acc[f][c][j];
      if constexpr(MODE==EP_BF16)           ((bf16*)Out)[idx] = f2bf(val);
      else if constexpr(MODE==EP_TANH_BF16) ((bf16*)Out)[idx] = f2bf(tanhf(val));
      else if constexpr(MODE==EP_NEGEXP_F32){ float w = -expf(val + bias[col]); ((float*)Out)[idx] = fmaxf(w, -20.f); }
      else if constexpr(MODE==EP_RES_F32)   ((float*)Out)[idx] = auxf[idx] + val;
      else if constexpr(MODE==EP_RELU2_BF16){ float m = fmaxf(val,0.f); ((bf16*)Out)[idx] = f2bf(m*m); }
      else if constexpr(MODE==EP_SIG_BF16)  ((bf16*)Out)[idx] = f2bf(1.f/(1.f+expf(-val)));
      else if constexpr(MODE==EP_FINAL_F32) ((float*)Out)[idx] = auxf[idx] + bf2f(auxb[idx])*val;
    }
  }
}

// ---------------- WKV6 segment scan (sub-chunks of 64 tokens) ----------------
// P1: lane = k. Local decay-weighted KV sum M[k][v] (bf16 out) + total decay Dseg (fused old p0).
__global__ __launch_bounds__(64,2) void wkv_p1(const bf16* __restrict__ kbuf, const bf16* __restrict__ vbuf,
      const float* __restrict__ wd, bf16* __restrict__ Mseg, float* __restrict__ Dseg){
  int bhs = blockIdx.x; int bh = bhs/NSUB, sub = bhs%NSUB;
  int b = bh>>2, h = bh&3;
  int ln = threadIdx.x;
  __shared__ float vtile[16][128];
  float S[128];
  #pragma unroll
  for (int v=0;v<128;v++) S[v]=0.f;
  float csum = 0.f;
  int t0 = sub*SUB;
  size_t kqbase = ((size_t)b*TT + t0)*KD + h*64 + ln;
  float wnxt = wd[kqbase];
  unsigned short qnxt = ((const unsigned short*)kbuf)[kqbase];
  #pragma unroll 1
  for (int tile=0; tile<4; tile++){
    int tb = t0 + tile*16;
    __syncthreads();
    #pragma unroll
    for (int j=0;j<4;j++){
      int f = ln + j*64; int t = f>>4, c = (f&15)*8;
      u16x8 v8 = *(const u16x8*)&((const unsigned short*)vbuf)[((size_t)b*TT + tb + t)*VD + h*128 + c];
      #pragma unroll
      for (int e=0;e<8;e++) vtile[t][c+e] = bfbits(v8[e]);
    }
    __syncthreads();
    #pragma unroll 1
    for (int t=0;t<16;t++){
      float wcur = wnxt; unsigned short qcur = qnxt;
      int lt = tile*16 + t;
      if (lt < SUB-1){
        size_t gi = kqbase + (size_t)(lt+1)*KD;
        wnxt = wd[gi]; qnxt = ((const unsigned short*)kbuf)[gi];
      }
      csum += wcur;
      float e = expf(wcur), q = bfbits(qcur);
      #pragma unroll
      for (int v4=0; v4<32; v4++){
        float4 vv = *(const float4*)&vtile[t][v4*4];
        S[v4*4+0] = e*S[v4*4+0] + q*vv.x;
        S[v4*4+1] = e*S[v4*4+1] + q*vv.y;
        S[v4*4+2] = e*S[v4*4+2] + q*vv.z;
        S[v4*4+3] = e*S[v4*4+3] + q*vv.w;
      }
    }
  }
  bf16* M = Mseg + (size_t)bhs*8192 + (size_t)ln*128;
  #pragma unroll
  for (int v4=0; v4<32; v4++){
    ushort4 s4;
    s4.x = f2bfbits(S[v4*4+0]); s4.y = f2bfbits(S[v4*4+1]);
    s4.z = f2bfbits(S[v4*4+2]); s4.w = f2bfbits(S[v4*4+3]);
    *(ushort4*)&((unsigned short*)M)[v4*4] = s4;
  }
  Dseg[(size_t)bhs*64 + ln] = expf(csum);
}

// P2: sequential combine across sub-chunks, IN-PLACE bf16 (Mseg becomes Sstart)
__global__ __launch_bounds__(256) void wkv_p2(bf16* __restrict__ MS, const float* __restrict__ Dseg){
  int idx = blockIdx.x*256 + threadIdx.x;     // 32 bh * 8192 = 262144 threads
  int bh = idx>>13; int k = (idx>>7)&63; int v = idx&127;
  bf16* p = MS + (size_t)bh*NSUB*8192 + k*128 + v;
  const float* d = Dseg + (size_t)bh*NSUB*64 + k;
  float S = 0.f;
  float m = bf2f(p[0]); float D = d[0];
  #pragma unroll 1
  for (int seg=0; seg<NSUB; seg++){
    float mN=0.f, DN=0.f;
    if (seg < NSUB-1){ mN = bf2f(p[(size_t)(seg+1)*8192]); DN = d[(seg+1)*64]; }
    p[(size_t)seg*8192] = f2bf(S);
    S = D*S + m;
    m = mN; D = DN;
  }
}

// P3: outputs + fused GroupNorm + silu(g) gate. lane = 2 v-columns, vectorized uniform LDS reads.
__global__ __launch_bounds__(64,2) void wkv_p3(const bf16* __restrict__ rbuf, const bf16* __restrict__ kbuf,
     const bf16* __restrict__ vbuf, const float* __restrict__ wd, const bf16* __restrict__ Sstart,
     const float* __restrict__ uu, const bf16* __restrict__ gg,
     const float* __restrict__ gn_w, const float* __restrict__ gn_b, bf16* __restrict__ gated){
  int bhs = blockIdx.x; int bh = bhs/NSUB, sub = bhs%NSUB;
  int b = bh>>2, h = bh&3;
  int ln = threadIdx.x;
  __shared__ float ew[16][64], qk[16][64], rr[16][64], bu[16];
  __shared__ unsigned short vtb[16][128];
  float gnw0 = gn_w[h*128+ln], gnw1 = gn_w[h*128+64+ln];
  float gnb0 = gn_b[h*128+ln], gnb1 = gn_b[h*128+64+ln];
  float Sa[64], Sb[64];
  const unsigned short* Sst = (const unsigned short*)(Sstart + (size_t)bhs*8192);
  #pragma unroll
  for (int k=0;k<64;k++){ Sa[k]=bfbits(Sst[k*128+ln]); Sb[k]=bfbits(Sst[k*128+ln+64]); }
  int t0 = sub*SUB;
  #pragma unroll 1
  for (int tile=0; tile<4; tile++){
    int tb = t0 + tile*16;
    __syncthreads();
    #pragma unroll
    for (int j=0;j<4;j++){
      int f = ln + j*64; int t = f>>4, c = (f&15)*4;
      float4 w4 = *(const float4*)&wd[((size_t)b*TT + tb + t)*KD + h*64 + c];
      ew[t][c+0]=expf(w4.x); ew[t][c+1]=expf(w4.y); ew[t][c+2]=expf(w4.z); ew[t][c+3]=expf(w4.w);
    }
    #pragma unroll
    for (int j=0;j<2;j++){
      int f = ln + j*64; int t = f>>3, c = (f&7)*8;
      size_t gi = ((size_t)b*TT + tb + t)*KD + h*64 + c;
      u16x8 k8 = *(const u16x8*)&((const unsigned short*)kbuf)[gi];
      u16x8 r8 = *(const u16x8*)&((const unsigned short*)rbuf)[gi];
      float u8[8];
      *(float4*)&u8[0] = *(const float4*)&uu[h*64+c];
      *(float4*)&u8[4] = *(const float4*)&uu[h*64+c+4];
      float part = 0.f;
      #pragma unroll
      for (int e=0;e<8;e++){
        float qv = bfbits(k8[e]), rv = bfbits(r8[e]);
        qk[t][c+e]=qv; rr[t][c+e]=rv;
        part += rv*qv*u8[e];
      }
      part += __shfl_xor(part,1,64); part += __shfl_xor(part,2,64); part += __shfl_xor(part,4,64);
      if ((ln&7)==0) bu[t] = part;
    }
    #pragma unroll
    for (int j=0;j<4;j++){
      int f = ln + j*64; int t = f>>4, c = (f&15)*8;
      *(u16x8*)&vtb[t][c] = *(const u16x8*)&((const unsigned short*)vbuf)[((size_t)b*TT + tb + t)*VD + h*128 + c];
    }
    __syncthreads();
    #pragma unroll 1
    for (int t=0;t<16;t++){
      size_t go = ((size_t)b*TT + tb + t)*VD + h*128;
      unsigned short gra = ((const unsigned short*)gg)[go+ln];
      unsigned short grb = ((const unsigned short*)gg)[go+ln+64];
      float va = bfbits(vtb[t][ln]), vb = bfbits(vtb[t][ln+64]);
      float oa=0.f, ob=0.f;
      #pragma unroll
      for (int k4=0;k4<16;k4++){
        float4 e4 = *(const float4*)&ew[t][k4*4];
        float4 q4 = *(const float4*)&qk[t][k4*4];
        float4 r4 = *(const float4*)&rr[t][k4*4];
        int k = k4*4;
        oa += r4.x*Sa[k+0]; ob += r4.x*Sb[k+0]; Sa[k+0]=e4.x*Sa[k+0]+q4.x*va; Sb[k+0]=e4.x*Sb[k+0]+q4.x*vb;
        oa += r4.y*Sa[k+1]; ob += r4.y*Sb[k+1]; Sa[k+1]=e4.y*Sa[k+1]+q4.y*va; Sb[k+1]=e4.y*Sb[k+1]+q4.y*vb;
        oa += r4.z*Sa[k+2]; ob += r4.z*Sb[k+2]; Sa[k+2]=e4.z*Sa[k+2]+q4.z*va; Sb[k+2]=e4.z*Sb[k+2]+q4.z*vb;
        oa += r4.w*Sa[k+3]; ob += r4.w*Sb[k+3]; Sa[k+3]=e4.w*Sa[k+3]+q4.w*va; Sb[k+3]=e4.w*Sb[k+3]+q4.w*vb;
      }
      float bb = bu[t];
      oa += bb*va; ob += bb*vb;
      float s = oa+ob, ss = oa*oa+ob*ob;
      #pragma unroll
      for (int off=32; off; off>>=1){ s += __shfl_xor(s,off,64); ss += __shfl_xor(ss,off,64); }
      float mu = s*(1.f/128.f);
      float inv = rsqrtf(fmaxf(ss*(1.f/128.f) - mu*mu, 0.f) + 1e-5f);
      float xa = (oa-mu)*inv*gnw0 + gnb0;
      float xb = (ob-mu)*inv*gnw1 + gnb1;
      float ga = bfbits(gra), gb = bfbits(grb);
      xa *= ga/(1.f+expf(-ga));
      xb *= gb/(1.f+expf(-gb));
      gated[go+ln] = f2bf(xa);
      gated[go+ln+64] = f2bf(xb);
    }
  }
}

// ---------------- FFN lerp inputs (bf16 in/out) ----------------
__global__ void build_ffn_in(const bf16* __restrict__ hn, const float* __restrict__ mu_k,
                             const float* __restrict__ mu_r, bf16* __restrict__ kin, bf16* __restrict__ rin){
  size_t idx = (size_t)blockIdx.x*256 + threadIdx.x;
  int c = (int)(idx & (CC-1));
  size_t bt = idx >> 9;
  float hv = bf2f(hn[idx]);
  float hp = (bt & (TT-1)) ? bf2f(hn[idx - CC]) : 0.f;
  float d = hp - hv;
  kin[idx] = f2bf(hv + d*mu_k[c]);
  rin[idx] = f2bf(hv + d*mu_r[c]);
}

// ---------------- compact workspace arena (bytes), peak ~213 MiB ----------------
#define MiB 1048576ull
static constexpr size_t OFF_H1   = 0;           // bf16 BT*C (32)  ; scan: GATED ; FFN: RF
static constexpr size_t OFF_XX   = 32*MiB;      // bf16 BT*192 (12); scan: Dseg inside
static constexpr size_t OFF_DSEG = 32*MiB;      // f32 2048*64 (0.5), alias XX (dead by scan)
static constexpr size_t OFF_HM   = 44*MiB;      // bf16 BT*C (32)  ; scan: Mseg/Sstart bf16 ; FFN: HN
static constexpr size_t OFF_R    = 76*MiB;      // bf16 BT*256 (16); FFN: KIN low
static constexpr size_t OFF_K    = 92*MiB;      // bf16 BT*256 (16); FFN: KIN high
static constexpr size_t OFF_V    = 108*MiB;     // bf16 BT*512 (32); FFN: RIN
static constexpr size_t OFF_WD   = 140*MiB;     // f32 BT*256 (32) ; FFN: KF low
static constexpr size_t OFF_G    = 172*MiB;     // bf16 BT*512 (32); FFN: KF high
static constexpr size_t OFF_W1T  = 204*MiB;     // bf16 BT*64 (4)
static constexpr size_t WT_X1  = 208*MiB;
static constexpr size_t WT_R   = WT_X1  + 196608;
static constexpr size_t WT_K   = WT_R   + 262144;
static constexpr size_t WT_V   = WT_K   + 262144;
static constexpr size_t WT_G   = WT_V   + 524288;
static constexpr size_t WT_W1  = WT_G   + 524288;
static constexpr size_t WT_W2  = WT_W1  + 65536;
static constexpr size_t WT_O   = WT_W2  + 32768;
static constexpr size_t WT_KEY = WT_O   + 524288;
static constexpr size_t WT_REC = WT_KEY + 1048576;
static constexpr size_t WT_VAL = WT_REC + 524288;
static constexpr size_t WS_NEED = WT_VAL + 1048576;

extern "C" void kernel_launch(void* const* d_in, const int* in_sizes, int n_in,
                              void* d_out, int out_size, void* d_ws, size_t ws_size,
                              hipStream_t stream){
  (void)in_sizes; (void)n_in; (void)out_size;
  if (ws_size < WS_NEED) return;   // clean failure instead of OOB fault
  const float* x      = (const float*)d_in[0];
  const float* ln1w   = (const float*)d_in[1];
  const float* ln1b   = (const float*)d_in[2];
  const float* mu_x   = (const float*)d_in[3];
  const float* W_x1   = (const float*)d_in[4];
  const float* W_x2   = (const float*)d_in[5];
  const float* x_bias = (const float*)d_in[6];
  const float* W_r    = (const float*)d_in[7];
  const float* W_k    = (const float*)d_in[8];
  const float* W_v    = (const float*)d_in[9];
  const float* W_g    = (const float*)d_in[10];
  const float* W_w1   = (const float*)d_in[11];
  const float* W_w2   = (const float*)d_in[12];
  const float* b_w2   = (const float*)d_in[13];
  const float* u      = (const float*)d_in[14];
  const float* gn_w   = (const float*)d_in[15];
  const float* gn_b   = (const float*)d_in[16];
  const float* W_o    = (const float*)d_in[17];
  const float* ln2w   = (const float*)d_in[18];
  const float* ln2b   = (const float*)d_in[19];
  const float* mu_k   = (const float*)d_in[20];
  const float* W_key  = (const float*)d_in[21];
  const float* mu_r   = (const float*)d_in[22];
  const float* W_rec  = (const float*)d_in[23];
  const float* W_val  = (const float*)d_in[24];
  char* ws = (char*)d_ws;
  auto F  = [&](size_t off){ return (float*)(ws+off); };
  auto Bf = [&](size_t off){ return (bf16*)(ws+off); };
  float* h2 = (float*)d_out;   // attn-out residual lives in d_out

  auto wc = [&](const float* src, size_t dstoff, int K, int N, int Npad){
    int tot = K*Npad;
    wconv_t<<<(tot+255)/256, 256, 0, stream>>>(src, Bf(dstoff), K, N, Npad);
  };
  wc(W_x1, WT_X1, 512, 160, 192);
  wc(W_r,  WT_R,  512, 256, 256);
  wc(W_k,  WT_K,  512, 256, 256);
  wc(W_v,  WT_V,  512, 512, 512);
  wc(W_g,  WT_G,  512, 512, 512);
  wc(W_w1, WT_W1, 512, 64, 64);
  wc(W_w2, WT_W2, 64, 256, 256);
  wc(W_o,  WT_O,  512, 512, 512);
  wc(W_key,WT_KEY,512, 1024, 1024);
  wc(W_rec,WT_REC,512, 512, 512);
  wc(W_val,WT_VAL,1024, 512, 512);

  // ---- attention pre-projections ----
  ln_bf16<<<BT,256,0,stream>>>(x, ln1w, ln1b, Bf(OFF_H1));
  build_xm<<<BT*CC/256,256,0,stream>>>(Bf(OFF_H1), mu_x, Bf(OFF_HM));
  gemm_bf16<EP_TANH_BF16><<<dim3(BT/128,3),256,0,stream>>>(Bf(OFF_HM), Bf(WT_X1), Bf(OFF_XX), 192,512, nullptr,nullptr,nullptr);

  for (int i=0;i<5;i++){
    build_hm<<<dim3(BT/16,4),128,0,stream>>>(Bf(OFF_H1), Bf(OFF_XX)+i*32, W_x2 + (size_t)i*32*CC, x_bias + i*CC, Bf(OFF_HM));
    if (i==0)      gemm_bf16<EP_BF16><<<dim3(BT/128,4),256,0,stream>>>(Bf(OFF_HM), Bf(WT_R), Bf(OFF_R), 256,512, nullptr,nullptr,nullptr);
    else if (i==1){
      gemm_bf16<EP_TANH_BF16><<<dim3(BT/128,1),256,0,stream>>>(Bf(OFF_HM), Bf(WT_W1), Bf(OFF_W1T), 64,512, nullptr,nullptr,nullptr);
      gemm_bf16<EP_NEGEXP_F32><<<dim3(BT/128,4),256,0,stream>>>(Bf(OFF_W1T), Bf(WT_W2), F(OFF_WD), 256,64, nullptr,nullptr,b_w2);
    }
    else if (i==2) gemm_bf16<EP_BF16><<<dim3(BT/128,4),256,0,stream>>>(Bf(OFF_HM), Bf(WT_K), Bf(OFF_K), 256,512, nullptr,nullptr,nullptr);
    else if (i==3) gemm_bf16<EP_BF16><<<dim3(BT/128,8),256,0,stream>>>(Bf(OFF_HM), Bf(WT_V), Bf(OFF_V), 512,512, nullptr,nullptr,nullptr);
    else           gemm_bf16<EP_BF16><<<dim3(BT/128,8),256,0,stream>>>(Bf(OFF_HM), Bf(WT_G), Bf(OFF_G), 512,512, nullptr,nullptr,nullptr);
  }

  // ---- WKV6 segment scan (SUB=64) ----
  wkv_p1<<<BB*4*NSUB,64,0,stream>>>(Bf(OFF_K), Bf(OFF_V), F(OFF_WD), Bf(OFF_HM), F(OFF_DSEG));
  wkv_p2<<<BB*4*8192/256,256,0,stream>>>(Bf(OFF_HM), F(OFF_DSEG));
  wkv_p3<<<BB*4*NSUB,64,0,stream>>>(Bf(OFF_R), Bf(OFF_K), Bf(OFF_V), F(OFF_WD), Bf(OFF_HM), u,
                                    Bf(OFF_G), gn_w, gn_b, Bf(OFF_H1));

  // ---- output projection + residual -> h2 (in d_out) ----
  gemm_bf16<EP_RES_F32><<<dim3(BT/128,8),256,0,stream>>>(Bf(OFF_H1), Bf(WT_O), h2, 512,512, x,nullptr,nullptr);

  // ---- channel mixing (FFN) ----
  ln_bf16<<<BT,256,0,stream>>>(h2, ln2w, ln2b, Bf(OFF_HM));
  build_ffn_in<<<BT*CC/256,256,0,stream>>>(Bf(OFF_HM), mu_k, mu_r, Bf(OFF_R), Bf(OFF_V));
  gemm_bf16<EP_RELU2_BF16><<<dim3(BT/128,16),256,0,stream>>>(Bf(OFF_R), Bf(WT_KEY), Bf(OFF_WD), 1024,512, nullptr,nullptr,nullptr);
  gemm_bf16<EP_SIG_BF16><<<dim3(BT/128,8),256,0,stream>>>(Bf(OFF_V), Bf(WT_REC), Bf(OFF_H1), 512,512, nullptr,nullptr,nullptr);
  gemm_bf16<EP_FINAL_F32><<<dim3(BT/128,8),256,0,stream>>>(Bf(OFF_WD), Bf(WT_VAL), h2, 512,1024, h2, Bf(OFF_H1), nullptr);
}

// Round 4
// 1053.630 us; speedup vs baseline: 1.6232x; 1.0440x over previous
//
#include <hip/hip_runtime.h>
#include <hip/hip_bf16.h>
#include <math.h>

#define BB 8
#define TT 4096
#define CC 512
#define BT (BB*TT)
#define KD 256
#define VD 512
#define NSUB 128
#define SUB 32

using bf16 = __hip_bfloat16;
typedef __attribute__((ext_vector_type(4))) float f32x4;
typedef __attribute__((ext_vector_type(8))) short s16x8;
typedef __attribute__((ext_vector_type(8))) unsigned short u16x8;
typedef const __attribute__((address_space(1))) unsigned int gu32;
typedef __attribute__((address_space(3))) unsigned int lu32;

static __device__ __forceinline__ float bf2f(bf16 x){ return __bfloat162float(x); }
static __device__ __forceinline__ bf16 f2bf(float x){ return __float2bfloat16(x); }
static __device__ __forceinline__ float bfbits(unsigned short u){
  union { unsigned int i; float f; } x; x.i = ((unsigned int)u)<<16; return x.f;
}
static __device__ __forceinline__ unsigned short f2bfbits(float f){
  union { bf16 b; unsigned short u; } x; x.b = f2bf(f); return x.u;
}
static __device__ __forceinline__ void gload16(const void* g, void* l){
  __builtin_amdgcn_global_load_lds((gu32*)g, (lu32*)l, 16, 0, 0);
}

// ---------------- weight convert+transpose: dst[Npad][K] = src[k][n] (bf16, zero pad) ---------
__global__ void wconv_t(const float* __restrict__ src, bf16* __restrict__ dst, int K, int N, int Npad){
  int idx = blockIdx.x*256 + threadIdx.x;
  if (idx >= K*Npad) return;
  int n = idx / K, k = idx % K;
  float v = (n < N) ? src[(size_t)k*N + n] : 0.f;
  dst[idx] = f2bf(v);
}

// ---------------- LayerNorm over C=512, block per row, bf16 out ----------------
__global__ __launch_bounds__(256) void ln_bf16(const float* __restrict__ x, const float* __restrict__ w,
                                               const float* __restrict__ b, bf16* __restrict__ out){
  int bt = blockIdx.x;
  const float* row = x + (size_t)bt*CC;
  int t = threadIdx.x;
  float a0 = row[t], a1 = row[t+256];
  float s = a0 + a1, ss = a0*a0 + a1*a1;
  for (int off=32; off; off>>=1){ s += __shfl_down(s, off, 64); ss += __shfl_down(ss, off, 64); }
  __shared__ float ps[4], pss[4];
  int wv = t>>6, ln = t&63;
  if (ln==0){ ps[wv]=s; pss[wv]=ss; }
  __syncthreads();
  if (t==0){
    float S=ps[0]+ps[1]+ps[2]+ps[3], SS=pss[0]+pss[1]+pss[2]+pss[3];
    float mu = S/CC; float var = SS/CC - mu*mu;
    ps[0]=mu; pss[0]=rsqrtf(var+1e-5f);
  }
  __syncthreads();
  float mu = ps[0], inv = pss[0];
  out[(size_t)bt*CC + t]     = f2bf((a0-mu)*inv*w[t]+b[t]);
  out[(size_t)bt*CC + t+256] = f2bf((a1-mu)*inv*w[t+256]+b[t+256]);
}

// ---------------- xm = h + (shift(h)-h)*mu_x  (bf16 in/out) ----------------
__global__ void build_xm(const bf16* __restrict__ h, const float* __restrict__ mu_x, bf16* __restrict__ xm){
  size_t idx = (size_t)blockIdx.x*256 + threadIdx.x;
  int c = (int)(idx & (CC-1));
  size_t bt = idx >> 9;
  float hv = bf2f(h[idx]);
  float hp = (bt & (TT-1)) ? bf2f(h[idx - CC]) : 0.f;
  xm[idx] = f2bf(hv + (hp - hv)*mu_x[c]);
}

// ---------------- single lerp-mix build: hm = h + (hprev-h)*(xx_i @ W_x2[i] + bias_i) -------
__global__ __launch_bounds__(128) void build_hm(const bf16* __restrict__ h, const bf16* __restrict__ xx,
        const float* __restrict__ W_x2i, const float* __restrict__ x_biasi, bf16* __restrict__ hm){
  int bt0 = blockIdx.x*16;
  int c = blockIdx.y*128 + threadIdx.x;
  float W[32];
  #pragma unroll
  for (int r=0;r<32;r++) W[r] = W_x2i[(size_t)r*CC + c];
  float bia = x_biasi[c];
  #pragma unroll 1
  for (int j=0;j<16;j++){
    int bt = bt0+j;
    float hv = bf2f(h[(size_t)bt*CC + c]);
    float hp = ((bt & (TT-1)) != 0) ? bf2f(h[(size_t)(bt-1)*CC + c]) : 0.f;
    const bf16* xr = xx + (size_t)bt*256;
    float acc = bia;
    #pragma unroll
    for (int r=0;r<32;r++) acc += bf2f(xr[r])*W[r];
    hm[(size_t)bt*CC + c] = f2bf(hv + (hp-hv)*acc);
  }
}

// ---------------- epilogue modes ----------------
enum {EP_BF16, EP_TANH_BF16, EP_NEGEXP_F32, EP_RES_F32, EP_RELU2_BF16, EP_SIG_BF16, EP_FINAL_F32};

// ---------------- m97-style 128x128 MFMA GEMM with global_load_lds staging -------------
// Out[M,N] = A[M,K] @ Bt[N,K]^T.  grid = 256*(N/128) linear, XCD-bijective swizzle. M=32768.
template<int MODE>
__global__ __launch_bounds__(256) void gemm128(
    const bf16* __restrict__ A, const bf16* __restrict__ Bt, void* __restrict__ Out,
    int N, int K, const float* __restrict__ auxf, const bf16* __restrict__ auxb)
{
  __shared__ bf16 Al[128][32];
  __shared__ bf16 Bl[128][32];
  int tid = threadIdx.x;
  int nbk = N>>7;
  int q8 = gridDim.x>>3;
  int o = (blockIdx.x & 7)*q8 + (blockIdx.x>>3);
  int nb = o % nbk, mb = o / nbk;
  int m0 = mb*128, n0 = nb*128;
  int wv = tid>>6, ln = tid&63;
  int wr = wv>>1, wc = wv&1;
  f32x4 acc[4][4];
  #pragma unroll
  for (int i=0;i<4;i++) for (int j=0;j<4;j++){ f32x4 z={0.f,0.f,0.f,0.f}; acc[i][j]=z; }
  int r0 = tid>>2, k0 = (tid&3)*8;
  const int nkt = K>>5;
  for (int kt=0; kt<nkt; kt++){
    const bf16* ga = A  + (size_t)(m0+r0)*K + kt*32 + k0;
    const bf16* gb = Bt + (size_t)(n0+r0)*K + kt*32 + k0;
    gload16(ga,                 (char*)&Al[0][0] + tid*16);
    gload16(ga + (size_t)64*K,  (char*)&Al[0][0] + (tid+256)*16);
    gload16(gb,                 (char*)&Bl[0][0] + tid*16);
    gload16(gb + (size_t)64*K,  (char*)&Bl[0][0] + (tid+256)*16);
    __syncthreads();
    int ks = (ln>>4)*8;
    s16x8 af[4], bq[4];
    #pragma unroll
    for (int i=0;i<4;i++){
      af[i] = *(const s16x8*)&Al[wr*64 + i*16 + (ln&15)][ks];
      bq[i] = *(const s16x8*)&Bl[wc*64 + i*16 + (ln&15)][ks];
    }
    #pragma unroll
    for (int mi=0;mi<4;mi++)
      #pragma unroll
      for (int ni=0;ni<4;ni++)
        acc[mi][ni] = __builtin_amdgcn_mfma_f32_16x16x32_bf16(af[mi], bq[ni], acc[mi][ni], 0,0,0);
    __syncthreads();
  }
  #pragma unroll
  for (int mi=0;mi<4;mi++)
    #pragma unroll
    for (int ni=0;ni<4;ni++){
      int col = n0 + wc*64 + ni*16 + (ln&15);
      int rb  = m0 + wr*64 + mi*16 + (ln>>4)*4;
      #pragma unroll
      for (int j=0;j<4;j++){
        size_t idx = (size_t)(rb+j)*N + col;
        float val = acc[mi][ni][j];
        if constexpr(MODE==EP_BF16)           ((bf16*)Out)[idx] = f2bf(val);
        else if constexpr(MODE==EP_TANH_BF16) ((bf16*)Out)[idx] = f2bf(tanhf(val));
        else if constexpr(MODE==EP_RES_F32)   ((float*)Out)[idx] = auxf[idx] + val;
        else if constexpr(MODE==EP_RELU2_BF16){ float m = fmaxf(val,0.f); ((bf16*)Out)[idx] = f2bf(m*m); }
        else if constexpr(MODE==EP_SIG_BF16)  ((bf16*)Out)[idx] = f2bf(1.f/(1.f+expf(-val)));
        else if constexpr(MODE==EP_FINAL_F32) ((float*)Out)[idx] = auxf[idx] + bf2f(auxb[idx])*val;
      }
    }
}

// ---------------- small-N GEMM (kept from r2, used for W1 N=64 and W2 K=64) -------------
template<int MODE>
__global__ __launch_bounds__(256) void gemm_bf16(
    const bf16* __restrict__ A, const bf16* __restrict__ Bt, void* __restrict__ Out,
    int N, int K, const float* __restrict__ auxf, const bf16* __restrict__ auxb,
    const float* __restrict__ bias)
{
  __shared__ bf16 Al[128][40];
  __shared__ bf16 Bl[64][40];
  int tid = threadIdx.x;
  int m0 = blockIdx.x*128, n0 = blockIdx.y*64;
  int wv = tid>>6, ln = tid&63;
  f32x4 acc[2][4];
  #pragma unroll
  for(int f=0;f<2;f++) for(int c=0;c<4;c++){ f32x4 z = {0.f,0.f,0.f,0.f}; acc[f][c]=z; }
  const int nkt = K>>5;
  for (int kt=0; kt<nkt; kt++){
    __syncthreads();
    {
      int c0 = tid, c1 = tid+256;
      int r = c0>>2, ko=(c0&3)*8;
      *(uint4*)&Al[r][ko] = *(const uint4*)&A[(size_t)(m0+r)*K + kt*32 + ko];
      r = c1>>2; ko=(c1&3)*8;
      *(uint4*)&Al[r][ko] = *(const uint4*)&A[(size_t)(m0+r)*K + kt*32 + ko];
      r = tid>>2; ko=(tid&3)*8;
      *(uint4*)&Bl[r][ko] = *(const uint4*)&Bt[(size_t)(n0+r)*K + kt*32 + ko];
    }
    __syncthreads();
    int ks = (ln>>4)*8;
    s16x8 af0 = *(const s16x8*)&Al[wv*32 + (ln&15)][ks];
    s16x8 af1 = *(const s16x8*)&Al[wv*32 + 16 + (ln&15)][ks];
    #pragma unroll
    for (int c=0;c<4;c++){
      s16x8 bfr = *(const s16x8*)&Bl[c*16 + (ln&15)][ks];
      acc[0][c] = __builtin_amdgcn_mfma_f32_16x16x32_bf16(af0, bfr, acc[0][c], 0,0,0);
      acc[1][c] = __builtin_amdgcn_mfma_f32_16x16x32_bf16(af1, bfr, acc[1][c], 0,0,0);
    }
  }
  #pragma unroll
  for (int f=0; f<2; f++) for (int c=0;c<4;c++){
    int col = n0 + c*16 + (ln&15);
    int rbase = m0 + wv*32 + f*16 + (ln>>4)*4;
    #pragma unroll
    for (int j=0;j<4;j++){
      size_t idx = (size_t)(rbase+j)*N + col;
      float val = acc[f][c][j];
      if constexpr(MODE==EP_TANH_BF16)      ((bf16*)Out)[idx] = f2bf(tanhf(val));
      else if constexpr(MODE==EP_NEGEXP_F32){ float w = -expf(val + bias[col]); ((float*)Out)[idx] = fmaxf(w, -20.f); }
    }
  }
}

// ---------------- WKV6 segment scan (sub-chunks of 32 tokens, NSUB=128) ----------------
// P1: lane = k. Local decay-weighted KV sum M[k][v] (bf16, into d_out) + chunk decay Dseg.
__global__ __launch_bounds__(64) void wkv_p1(const bf16* __restrict__ kbuf, const bf16* __restrict__ vbuf,
      const float* __restrict__ wd, bf16* __restrict__ Mseg, float* __restrict__ Dseg){
  int bhs = blockIdx.x; int bh = bhs>>7, sub = bhs&127;
  int b = bh>>2, h = bh&3;
  int ln = threadIdx.x;
  __shared__ float vtile[16][132];
  int t0 = sub*SUB;
  size_t kqbase = ((size_t)b*TT + t0)*KD + h*64 + ln;
  float csum = 0.f;
  float S[128];
  #pragma unroll
  for (int v=0;v<128;v++) S[v]=0.f;
  float wnxt = wd[kqbase];
  unsigned short qnxt = ((const unsigned short*)kbuf)[kqbase];
  #pragma unroll 1
  for (int tile=0; tile<2; tile++){
    int tb = t0 + tile*16;
    __syncthreads();
    #pragma unroll
    for (int j=0;j<4;j++){
      int f = ln + j*64; int t = f>>4, c8 = (f&15)*8;
      u16x8 v8 = *(const u16x8*)&((const unsigned short*)vbuf)[((size_t)b*TT + tb + t)*VD + h*128 + c8];
      float4 lo, hi;
      lo.x=bfbits(v8[0]); lo.y=bfbits(v8[1]); lo.z=bfbits(v8[2]); lo.w=bfbits(v8[3]);
      hi.x=bfbits(v8[4]); hi.y=bfbits(v8[5]); hi.z=bfbits(v8[6]); hi.w=bfbits(v8[7]);
      *(float4*)&vtile[t][c8]   = lo;
      *(float4*)&vtile[t][c8+4] = hi;
    }
    __syncthreads();
    #pragma unroll 1
    for (int tt=0;tt<16;tt++){
      int lt = tile*16+tt;
      float wcur = wnxt; unsigned short qcur = qnxt;
      if (lt < SUB-1){
        size_t gi = kqbase + (size_t)(lt+1)*KD;
        wnxt = wd[gi]; qnxt = ((const unsigned short*)kbuf)[gi];
      }
      csum += wcur;
      float e = expf(wcur), qv = bfbits(qcur);
      #pragma unroll
      for (int v4=0;v4<32;v4++){
        float4 vv = *(const float4*)&vtile[tt][v4*4];
        S[v4*4+0] = e*S[v4*4+0] + qv*vv.x;
        S[v4*4+1] = e*S[v4*4+1] + qv*vv.y;
        S[v4*4+2] = e*S[v4*4+2] + qv*vv.z;
        S[v4*4+3] = e*S[v4*4+3] + qv*vv.w;
      }
    }
  }
  bf16* M = Mseg + (size_t)bhs*8192 + (size_t)ln*128;
  #pragma unroll
  for (int v4=0; v4<32; v4++){
    ushort4 s4;
    s4.x = f2bfbits(S[v4*4+0]); s4.y = f2bfbits(S[v4*4+1]);
    s4.z = f2bfbits(S[v4*4+2]); s4.w = f2bfbits(S[v4*4+3]);
    *(ushort4*)&((unsigned short*)M)[v4*4] = s4;
  }
  Dseg[(size_t)bhs*64 + ln] = expf(csum);
}

// P2: sequential combine across sub-chunks, IN-PLACE bf16 (Mseg becomes Sstart)
__global__ __launch_bounds__(256) void wkv_p2(bf16* __restrict__ MS, const float* __restrict__ Dseg){
  int idx = blockIdx.x*256 + threadIdx.x;
  int bh = idx>>13; int k = (idx>>7)&63; int v = idx&127;
  bf16* p = MS + (size_t)bh*NSUB*8192 + k*128 + v;
  const float* d = Dseg + (size_t)bh*NSUB*64 + k;
  float S = 0.f;
  float m = bf2f(p[0]); float D = d[0];
  #pragma unroll 1
  for (int seg=0; seg<NSUB; seg++){
    float mN=0.f, DN=0.f;
    if (seg < NSUB-1){ mN = bf2f(p[(size_t)(seg+1)*8192]); DN = d[(seg+1)*64]; }
    p[(size_t)seg*8192] = f2bf(S);
    S = D*S + m;
    m = mN; D = DN;
  }
}

// P3: outputs + fused GroupNorm + silu(g) gate. lane = 2 v-columns, 8-token tiles.
__global__ __launch_bounds__(64) void wkv_p3(const bf16* __restrict__ rbuf, const bf16* __restrict__ kbuf,
     const bf16* __restrict__ vbuf, const float* __restrict__ wd, const bf16* __restrict__ Sstart,
     const float* __restrict__ uu, const bf16* __restrict__ gg,
     const float* __restrict__ gn_w, const float* __restrict__ gn_b, bf16* __restrict__ gated){
  int bhs = blockIdx.x; int bh = bhs>>7, sub = bhs&127;
  int b = bh>>2, h = bh&3;
  int ln = threadIdx.x;
  __shared__ float ew[8][68], qk[8][68], rr[8][68], bu[8];
  __shared__ unsigned short vtb[8][128];
  float gnw0 = gn_w[h*128+ln], gnw1 = gn_w[h*128+64+ln];
  float gnb0 = gn_b[h*128+ln], gnb1 = gn_b[h*128+64+ln];
  float u8[8];
  {
    int c = (ln&7)*8;
    *(float4*)&u8[0] = *(const float4*)&uu[h*64+c];
    *(float4*)&u8[4] = *(const float4*)&uu[h*64+c+4];
  }
  float Sa[64], Sb[64];
  const unsigned short* Sst = (const unsigned short*)Sstart + (size_t)bhs*8192;
  #pragma unroll
  for (int k=0;k<64;k++){ Sa[k]=bfbits(Sst[k*128+ln]); Sb[k]=bfbits(Sst[k*128+ln+64]); }
  int t0 = sub*SUB;
  #pragma unroll 1
  for (int tile=0; tile<4; tile++){
    int tb = t0 + tile*8;
    __syncthreads();
    #pragma unroll
    for (int j=0;j<2;j++){
      int f = ln + j*64; int t = f>>4, c4 = (f&15)*4;
      float4 w4 = *(const float4*)&wd[((size_t)b*TT + tb + t)*KD + h*64 + c4];
      ew[t][c4+0]=expf(w4.x); ew[t][c4+1]=expf(w4.y); ew[t][c4+2]=expf(w4.z); ew[t][c4+3]=expf(w4.w);
    }
    {
      int t = ln>>3, c = (ln&7)*8;
      size_t gi = ((size_t)b*TT + tb + t)*KD + h*64 + c;
      u16x8 k8 = *(const u16x8*)&((const unsigned short*)kbuf)[gi];
      u16x8 r8 = *(const u16x8*)&((const unsigned short*)rbuf)[gi];
      float part = 0.f;
      #pragma unroll
      for (int e=0;e<8;e++){
        float qv = bfbits(k8[e]), rv = bfbits(r8[e]);
        qk[t][c+e]=qv; rr[t][c+e]=rv;
        part += rv*qv*u8[e];
      }
      part += __shfl_xor(part,1,64); part += __shfl_xor(part,2,64); part += __shfl_xor(part,4,64);
      if ((ln&7)==0) bu[t] = part;
    }
    #pragma unroll
    for (int j=0;j<2;j++){
      int f = ln + j*64; int t = f>>4, c = (f&15)*8;
      *(u16x8*)&vtb[t][c] = *(const u16x8*)&((const unsigned short*)vbuf)[((size_t)b*TT + tb + t)*VD + h*128 + c];
    }
    __syncthreads();
    #pragma unroll 1
    for (int t=0;t<8;t++){
      size_t go = ((size_t)b*TT + tb + t)*VD + h*128;
      unsigned short gra = ((const unsigned short*)gg)[go+ln];
      unsigned short grb = ((const unsigned short*)gg)[go+ln+64];
      float va = bfbits(vtb[t][ln]), vb = bfbits(vtb[t][ln+64]);
      float oa=0.f, ob=0.f;
      #pragma unroll
      for (int k4=0;k4<16;k4++){
        float4 e4 = *(const float4*)&ew[t][k4*4];
        float4 q4 = *(const float4*)&qk[t][k4*4];
        float4 r4 = *(const float4*)&rr[t][k4*4];
        int k = k4*4;
        oa += r4.x*Sa[k+0]; ob += r4.x*Sb[k+0]; Sa[k+0]=e4.x*Sa[k+0]+q4.x*va; Sb[k+0]=e4.x*Sb[k+0]+q4.x*vb;
        oa += r4.y*Sa[k+1]; ob += r4.y*Sb[k+1]; Sa[k+1]=e4.y*Sa[k+1]+q4.y*va; Sb[k+1]=e4.y*Sb[k+1]+q4.y*vb;
        oa += r4.z*Sa[k+2]; ob += r4.z*Sb[k+2]; Sa[k+2]=e4.z*Sa[k+2]+q4.z*va; Sb[k+2]=e4.z*Sb[k+2]+q4.z*vb;
        oa += r4.w*Sa[k+3]; ob += r4.w*Sb[k+3]; Sa[k+3]=e4.w*Sa[k+3]+q4.w*va; Sb[k+3]=e4.w*Sb[k+3]+q4.w*vb;
      }
      float bb = bu[t];
      oa += bb*va; ob += bb*vb;
      float s = oa+ob, ss = oa*oa+ob*ob;
      #pragma unroll
      for (int off=32; off; off>>=1){ s += __shfl_xor(s,off,64); ss += __shfl_xor(ss,off,64); }
      float mu = s*(1.f/128.f);
      float inv = rsqrtf(fmaxf(ss*(1.f/128.f) - mu*mu, 0.f) + 1e-5f);
      float xa = (oa-mu)*inv*gnw0 + gnb0;
      float xb = (ob-mu)*inv*gnw1 + gnb1;
      float ga = bfbits(gra), gb = bfbits(grb);
      xa *= ga/(1.f+expf(-ga));
      xb *= gb/(1.f+expf(-gb));
      gated[go+ln] = f2bf(xa);
      gated[go+ln+64] = f2bf(xb);
    }
  }
}

// ---------------- FFN lerp inputs (bf16 in/out) ----------------
__global__ void build_ffn_in(const bf16* __restrict__ hn, const float* __restrict__ mu_k,
                             const float* __restrict__ mu_r, bf16* __restrict__ kin, bf16* __restrict__ rin){
  size_t idx = (size_t)blockIdx.x*256 + threadIdx.x;
  int c = (int)(idx & (CC-1));
  size_t bt = idx >> 9;
  float hv = bf2f(hn[idx]);
  float hp = (bt & (TT-1)) ? bf2f(hn[idx - CC]) : 0.f;
  float d = hp - hv;
  kin[idx] = f2bf(hv + d*mu_k[c]);
  rin[idx] = f2bf(hv + d*mu_r[c]);
}

// ---------------- workspace arena (bytes), peak ~217.3 MiB; Mseg lives in d_out ----------------
#define MiB 1048576ull
static constexpr size_t OFF_H1   = 0;           // bf16 BT*C (32)  ; p3 out GATED ; FFN RF
static constexpr size_t OFF_XX   = 32*MiB;      // bf16 BT*256 (16); dead by scan
static constexpr size_t OFF_DSEG = 32*MiB;      // f32 4096*64 (1) alias XX
static constexpr size_t OFF_HM   = 48*MiB;      // bf16 BT*C (32)  ; FFN HN
static constexpr size_t OFF_R    = 80*MiB;      // bf16 BT*256 (16); FFN KIN (spans R+K)
static constexpr size_t OFF_K    = 96*MiB;      // bf16 BT*256 (16)
static constexpr size_t OFF_V    = 112*MiB;     // bf16 BT*512 (32); FFN RIN
static constexpr size_t OFF_WD   = 144*MiB;     // f32 BT*256 (32) ; FFN KF low
static constexpr size_t OFF_G    = 176*MiB;     // bf16 BT*512 (32); FFN KF high
static constexpr size_t OFF_W1T  = 208*MiB;     // bf16 BT*64 (4)
static constexpr size_t WT_X1  = 212*MiB;            // 512x256 bf16
static constexpr size_t WT_R   = WT_X1  + 262144;
static constexpr size_t WT_K   = WT_R   + 262144;
static constexpr size_t WT_V   = WT_K   + 262144;
static constexpr size_t WT_G   = WT_V   + 524288;
static constexpr size_t WT_W1  = WT_G   + 524288;
static constexpr size_t WT_W2  = WT_W1  + 65536;
static constexpr size_t WT_O   = WT_W2  + 32768;
static constexpr size_t WT_KEY = WT_O   + 524288;
static constexpr size_t WT_REC = WT_KEY + 1048576;
static constexpr size_t WT_VAL = WT_REC + 524288;
static constexpr size_t WS_NEED = WT_VAL + 1048576;

extern "C" void kernel_launch(void* const* d_in, const int* in_sizes, int n_in,
                              void* d_out, int out_size, void* d_ws, size_t ws_size,
                              hipStream_t stream){
  (void)in_sizes; (void)n_in; (void)out_size;
  if (ws_size < WS_NEED) return;
  const float* x      = (const float*)d_in[0];
  const float* ln1w   = (const float*)d_in[1];
  const float* ln1b   = (const float*)d_in[2];
  const float* mu_x   = (const float*)d_in[3];
  const float* W_x1   = (const float*)d_in[4];
  const float* W_x2   = (const float*)d_in[5];
  const float* x_bias = (const float*)d_in[6];
  const float* W_r    = (const float*)d_in[7];
  const float* W_k    = (const float*)d_in[8];
  const float* W_v    = (const float*)d_in[9];
  const float* W_g    = (const float*)d_in[10];
  const float* W_w1   = (const float*)d_in[11];
  const float* W_w2   = (const float*)d_in[12];
  const float* b_w2   = (const float*)d_in[13];
  const float* u      = (const float*)d_in[14];
  const float* gn_w   = (const float*)d_in[15];
  const float* gn_b   = (const float*)d_in[16];
  const float* W_o    = (const float*)d_in[17];
  const float* ln2w   = (const float*)d_in[18];
  const float* ln2b   = (const float*)d_in[19];
  const float* mu_k   = (const float*)d_in[20];
  const float* W_key  = (const float*)d_in[21];
  const float* mu_r   = (const float*)d_in[22];
  const float* W_rec  = (const float*)d_in[23];
  const float* W_val  = (const float*)d_in[24];
  char* ws = (char*)d_ws;
  auto F  = [&](size_t off){ return (float*)(ws+off); };
  auto Bf = [&](size_t off){ return (bf16*)(ws+off); };
  float* h2 = (float*)d_out;        // attn-out residual lives in d_out
  bf16* Mseg = (bf16*)d_out;        // scan summaries alias d_out (dead before O-gemm)

  auto wc = [&](const float* src, size_t dstoff, int K, int N, int Npad){
    int tot = K*Npad;
    wconv_t<<<(tot+255)/256, 256, 0, stream>>>(src, Bf(dstoff), K, N, Npad);
  };
  wc(W_x1, WT_X1, 512, 160, 256);
  wc(W_r,  WT_R,  512, 256, 256);
  wc(W_k,  WT_K,  512, 256, 256);
  wc(W_v,  WT_V,  512, 512, 512);
  wc(W_g,  WT_G,  512, 512, 512);
  wc(W_w1, WT_W1, 512, 64, 64);
  wc(W_w2, WT_W2, 64, 256, 256);
  wc(W_o,  WT_O,  512, 512, 512);
  wc(W_key,WT_KEY,512, 1024, 1024);
  wc(W_rec,WT_REC,512, 512, 512);
  wc(W_val,WT_VAL,1024, 512, 512);

  // ---- attention pre-projections ----
  ln_bf16<<<BT,256,0,stream>>>(x, ln1w, ln1b, Bf(OFF_H1));
  build_xm<<<BT*CC/256,256,0,stream>>>(Bf(OFF_H1), mu_x, Bf(OFF_HM));
  gemm128<EP_TANH_BF16><<<512,256,0,stream>>>(Bf(OFF_HM), Bf(WT_X1), Bf(OFF_XX), 256,512, nullptr,nullptr);

  for (int i=0;i<5;i++){
    build_hm<<<dim3(BT/16,4),128,0,stream>>>(Bf(OFF_H1), Bf(OFF_XX)+i*32, W_x2 + (size_t)i*32*CC, x_bias + i*CC, Bf(OFF_HM));
    if (i==0)      gemm128<EP_BF16><<<512,256,0,stream>>>(Bf(OFF_HM), Bf(WT_R), Bf(OFF_R), 256,512, nullptr,nullptr);
    else if (i==1){
      gemm_bf16<EP_TANH_BF16><<<dim3(BT/128,1),256,0,stream>>>(Bf(OFF_HM), Bf(WT_W1), Bf(OFF_W1T), 64,512, nullptr,nullptr,nullptr);
      gemm_bf16<EP_NEGEXP_F32><<<dim3(BT/128,4),256,0,stream>>>(Bf(OFF_W1T), Bf(WT_W2), F(OFF_WD), 256,64, nullptr,nullptr,b_w2);
    }
    else if (i==2) gemm128<EP_BF16><<<512,256,0,stream>>>(Bf(OFF_HM), Bf(WT_K), Bf(OFF_K), 256,512, nullptr,nullptr);
    else if (i==3) gemm128<EP_BF16><<<1024,256,0,stream>>>(Bf(OFF_HM), Bf(WT_V), Bf(OFF_V), 512,512, nullptr,nullptr);
    else           gemm128<EP_BF16><<<1024,256,0,stream>>>(Bf(OFF_HM), Bf(WT_G), Bf(OFF_G), 512,512, nullptr,nullptr);
  }

  // ---- WKV6 segment scan (SUB=32, NSUB=128); Mseg/Sstart in d_out ----
  wkv_p1<<<BB*4*NSUB,64,0,stream>>>(Bf(OFF_K), Bf(OFF_V), F(OFF_WD), Mseg, F(OFF_DSEG));
  wkv_p2<<<BB*4*8192/256,256,0,stream>>>(Mseg, F(OFF_DSEG));
  wkv_p3<<<BB*4*NSUB,64,0,stream>>>(Bf(OFF_R), Bf(OFF_K), Bf(OFF_V), F(OFF_WD), Mseg, u,
                                    Bf(OFF_G), gn_w, gn_b, Bf(OFF_H1));

  // ---- output projection + residual -> h2 (in d_out; overwrites Mseg) ----
  gemm128<EP_RES_F32><<<1024,256,0,stream>>>(Bf(OFF_H1), Bf(WT_O), h2, 512,512, x,nullptr);

  // ---- channel mixing (FFN) ----
  ln_bf16<<<BT,256,0,stream>>>(h2, ln2w, ln2b, Bf(OFF_HM));
  build_ffn_in<<<BT*CC/256,256,0,stream>>>(Bf(OFF_HM), mu_k, mu_r, Bf(OFF_R), Bf(OFF_V));
  gemm128<EP_RELU2_BF16><<<2048,256,0,stream>>>(Bf(OFF_R), Bf(WT_KEY), Bf(OFF_WD), 1024,512, nullptr,nullptr);
  gemm128<EP_SIG_BF16><<<1024,256,0,stream>>>(Bf(OFF_V), Bf(WT_REC), Bf(OFF_H1), 512,512, nullptr,nullptr);
  gemm128<EP_FINAL_F32><<<1024,256,0,stream>>>(Bf(OFF_WD), Bf(WT_VAL), h2, 512,1024, h2, Bf(OFF_H1));
}